// Round 1
// baseline (928.433 us; speedup 1.0000x reference)
//
#include <hip/hip_runtime.h>
#include <math.h>

#define NEG_SLOPE 0.2f

constexpr int F_IN  = 128;
constexpr int HC1   = 256;  // H*HID
constexpr int C1    = 64;
constexpr int HC2   = 160;  // H*CLS
constexpr int C2    = 40;
constexpr int NHEAD = 4;

// ---------------- edge-index dtype hedge ----------------
// Reference declares int64 edge_index; harness doc says integer -> int32.
// Detect at runtime: for int64 (values < 2^31), every odd 32-bit word is 0.
__global__ void detect_mode_kernel(const unsigned int* __restrict__ p, int nwords, int* mode) {
    __shared__ unsigned int red[256];
    unsigned int v = 0;
    for (int i = 1 + 2 * (int)threadIdx.x; i < nwords; i += 512) v |= p[i];
    red[threadIdx.x] = v;
    __syncthreads();
    for (int off = 128; off > 0; off >>= 1) {
        if (threadIdx.x < off) red[threadIdx.x] |= red[threadIdx.x + off];
        __syncthreads();
    }
    if (threadIdx.x == 0) *mode = (red[0] == 0u) ? 1 : 0;
}

__device__ __forceinline__ int edge_val(const void* p, int m64, long long i) {
    if (m64) return (int)((const long long*)p)[i];
    return ((const int*)p)[i];
}

// ---------------- column stats (mean, 1/std ddof=1) ----------------
__global__ void colstats_kernel(const float* __restrict__ x, float* __restrict__ stats, int N) {
    // 256 threads; block covers 256 rows; two threads per column.
    int col = threadIdx.x & 127;
    int r0 = blockIdx.x * 256;
    int rend = min(r0 + 256, N);
    float s = 0.f, q = 0.f;
    for (int r = r0 + (int)(threadIdx.x >> 7); r < rend; r += 2) {
        float v = x[(long)r * F_IN + col];
        s += v;
        q += v * v;
    }
    __shared__ float sh[256];
    sh[threadIdx.x] = s;
    __syncthreads();
    if (threadIdx.x < 128) atomicAdd(&stats[col], sh[threadIdx.x] + sh[threadIdx.x + 128]);
    __syncthreads();
    sh[threadIdx.x] = q;
    __syncthreads();
    if (threadIdx.x < 128) atomicAdd(&stats[128 + col], sh[threadIdx.x] + sh[threadIdx.x + 128]);
}

__global__ void finalize_stats_kernel(float* stats, int N) {
    int c = threadIdx.x;  // 128
    float s = stats[c], q = stats[128 + c];
    float mean = s / (float)N;
    float var = (q - s * s / (float)N) / (float)(N - 1);
    stats[c] = mean;
    stats[128 + c] = 1.0f / sqrtf(var);
}

__global__ void standardize_kernel(const float* __restrict__ x, const float* __restrict__ stats,
                                   float* __restrict__ xs, long total) {
    long i = (long)blockIdx.x * blockDim.x + threadIdx.x;
    if (i >= total) return;
    int col = (int)(i & (F_IN - 1));
    xs[i] = (x[i] - stats[col]) * stats[128 + col];
}

// ---------------- tiled fp32 SGEMM: C = A[MxK] * B[KxN] ----------------
// BM=BN=64, BK=16, 256 threads, 4x4 microtile. K must be a multiple of 16.
__global__ __launch_bounds__(256) void sgemm_kernel(const float* __restrict__ A,
                                                    const float* __restrict__ B,
                                                    float* __restrict__ C_,
                                                    int M, int N, int K) {
    __shared__ float As[16][68];  // [k][m], padded
    __shared__ float Bs[16][64];  // [k][n]
    int tid = threadIdx.x;
    int tx = tid & 15, ty = tid >> 4;
    int row0 = blockIdx.y * 64, col0 = blockIdx.x * 64;
    float acc[4][4] = {};

    for (int k0 = 0; k0 < K; k0 += 16) {
        // A tile: 64x16, float4 per thread
        {
            int l = tid * 4;
            int m = l >> 4;        // 0..63
            int kk = l & 15;       // 0,4,8,12
            int gr = row0 + m;
            float4 v = make_float4(0.f, 0.f, 0.f, 0.f);
            if (gr < M) v = *(const float4*)(A + (long)gr * K + k0 + kk);
            As[kk + 0][m] = v.x;
            As[kk + 1][m] = v.y;
            As[kk + 2][m] = v.z;
            As[kk + 3][m] = v.w;
        }
        // B tile: 16x64, float4 per thread
        {
            int l = tid * 4;
            int kk = l >> 6;       // 0..15
            int n = l & 63;        // 0,4,..,60
            int gc = col0 + n;
            float4 v = make_float4(0.f, 0.f, 0.f, 0.f);
            if (gc < N) v = *(const float4*)(B + (long)(k0 + kk) * N + gc);
            *(float4*)&Bs[kk][n] = v;
        }
        __syncthreads();
#pragma unroll
        for (int kk = 0; kk < 16; kk++) {
            float4 av = *(const float4*)&As[kk][ty * 4];
            float4 bv = *(const float4*)&Bs[kk][tx * 4];
            float a[4] = {av.x, av.y, av.z, av.w};
            float b[4] = {bv.x, bv.y, bv.z, bv.w};
#pragma unroll
            for (int i = 0; i < 4; i++)
#pragma unroll
                for (int j = 0; j < 4; j++) acc[i][j] += a[i] * b[j];
        }
        __syncthreads();
    }
#pragma unroll
    for (int i = 0; i < 4; i++) {
        int r = row0 + ty * 4 + i;
        if (r >= M) continue;
#pragma unroll
        for (int j = 0; j < 4; j++) {
            int c = col0 + tx * 4 + j;
            if (c < N) C_[(long)r * N + c] = acc[i][j];
        }
    }
}

// ---------------- attention scores a_src/a_dst ----------------
__global__ void att_kernel(const float* __restrict__ h, const float* __restrict__ att_s,
                           const float* __restrict__ att_d, float* __restrict__ as_,
                           float* __restrict__ ad_, int C) {
    int node = blockIdx.x;
    int lane = threadIdx.x;  // 64
    for (int hd = 0; hd < NHEAD; hd++) {
        float vs = 0.f, vd = 0.f;
        for (int c = lane; c < C; c += 64) {
            float v = h[(long)node * NHEAD * C + hd * C + c];
            vs += v * att_s[hd * C + c];
            vd += v * att_d[hd * C + c];
        }
        for (int off = 32; off > 0; off >>= 1) {
            vs += __shfl_down(vs, off);
            vd += __shfl_down(vd, off);
        }
        if (lane == 0) {
            as_[node * NHEAD + hd] = vs;
            ad_[node * NHEAD + hd] = vd;
        }
    }
}

// ---------------- CSR build over dst (self-loops via counts=1) ----------------
__global__ void init_counts_kernel(int* counts, int N) {
    int i = blockIdx.x * blockDim.x + threadIdx.x;
    if (i < N) counts[i] = 1;
}

__global__ void count_kernel(const void* __restrict__ ei, const int* __restrict__ mode, int E,
                             int* counts) {
    int e = blockIdx.x * blockDim.x + threadIdx.x;
    if (e >= E) return;
    int d = edge_val(ei, *mode, (long long)E + e);
    atomicAdd(&counts[d], 1);
}

__global__ void scan_kernel(const int* __restrict__ counts, int* __restrict__ offsets, int N) {
    __shared__ int buf[1024];
    __shared__ int carry;
    if (threadIdx.x == 0) carry = 0;
    __syncthreads();
    for (int base = 0; base < N; base += 1024) {
        int i = base + (int)threadIdx.x;
        int v = (i < N) ? counts[i] : 0;
        buf[threadIdx.x] = v;
        __syncthreads();
        for (int off = 1; off < 1024; off <<= 1) {
            int t = (threadIdx.x >= (unsigned)off) ? buf[threadIdx.x - off] : 0;
            __syncthreads();
            buf[threadIdx.x] += t;
            __syncthreads();
        }
        if (i < N) offsets[i + 1] = carry + buf[threadIdx.x];
        __syncthreads();
        if (threadIdx.x == 0) carry += buf[1023];
        __syncthreads();
    }
    if (threadIdx.x == 0) offsets[0] = 0;
}

__global__ void fill_csr_kernel(const void* __restrict__ ei, const int* __restrict__ mode, int E,
                                int N, const int* __restrict__ offsets, int* cursor,
                                int* __restrict__ csr) {
    int e = blockIdx.x * blockDim.x + threadIdx.x;
    if (e >= E + N) return;
    int m = *mode;
    int s, d;
    if (e < E) {
        s = edge_val(ei, m, e);
        d = edge_val(ei, m, (long long)E + e);
    } else {
        s = d = e - E;
    }
    int pos = offsets[d] + atomicAdd(&cursor[d], 1);
    csr[pos] = s;
}

// ---------------- per-node softmax + aggregation (no float atomics) ----------------
template <int HC, int C, bool RELU>
__global__ __launch_bounds__(256) void aggregate_kernel(
    const float* __restrict__ h, const float* __restrict__ a_src,
    const float* __restrict__ a_dst, const int* __restrict__ offsets,
    const int* __restrict__ csr_src, const float* __restrict__ bias, float* __restrict__ out) {
    int node = blockIdx.x;
    int tid = threadIdx.x;  // 256
    int start = offsets[node], end = offsets[node + 1];
    __shared__ float red[NHEAD * 256];
    __shared__ float inv_s[NHEAD];

    float ad[NHEAD];
#pragma unroll
    for (int hd = 0; hd < NHEAD; hd++) ad[hd] = a_dst[node * NHEAD + hd];

    // phase 1: softmax denominator per head (no max-shift needed: |logit| <~ 8)
    float ds[NHEAD] = {0.f, 0.f, 0.f, 0.f};
    for (int i = start + tid; i < end; i += 256) {
        int s = csr_src[i];
#pragma unroll
        for (int hd = 0; hd < NHEAD; hd++) {
            float e = a_src[s * NHEAD + hd] + ad[hd];
            e = e > 0.f ? e : NEG_SLOPE * e;
            ds[hd] += __expf(e);
        }
    }
#pragma unroll
    for (int hd = 0; hd < NHEAD; hd++) red[hd * 256 + tid] = ds[hd];
    __syncthreads();
    for (int off = 128; off > 0; off >>= 1) {
        if (tid < off) {
#pragma unroll
            for (int hd = 0; hd < NHEAD; hd++) red[hd * 256 + tid] += red[hd * 256 + tid + off];
        }
        __syncthreads();
    }
    if (tid < NHEAD) inv_s[tid] = 1.0f / red[tid * 256];
    __syncthreads();

    // phase 2: weighted gather-accumulate; thread = output channel
    if (tid < HC) {
        int hd = tid / C;
        float adh = ad[hd];
        float inv = inv_s[hd];
        float acc = 0.f;
        for (int i = start; i < end; i++) {
            int s = csr_src[i];
            float e = a_src[s * NHEAD + hd] + adh;
            e = e > 0.f ? e : NEG_SLOPE * e;
            acc += __expf(e) * h[(long)s * HC + tid];
        }
        float r = acc * inv + bias[tid];
        if (RELU) r = fmaxf(r, 0.f);
        out[(long)node * HC + tid] = r;
    }
}

// ---------------- launch ----------------
extern "C" void kernel_launch(void* const* d_in, const int* in_sizes, int n_in, void* d_out,
                              int out_size, void* d_ws, size_t ws_size, hipStream_t stream) {
    const float* x = (const float*)d_in[0];
    const void* ei = d_in[1];
    const float* W1 = (const float*)d_in[2];
    const float* attS1 = (const float*)d_in[3];
    const float* attD1 = (const float*)d_in[4];
    const float* b1 = (const float*)d_in[5];
    const float* W2 = (const float*)d_in[6];
    const float* attS2 = (const float*)d_in[7];
    const float* attD2 = (const float*)d_in[8];
    const float* b2 = (const float*)d_in[9];
    float* out = (float*)d_out;

    int N = in_sizes[0] / F_IN;  // 50000
    int E = in_sizes[1] / 2;     // 800000

    // workspace layout (all segments 16B aligned)
    float* ws = (float*)d_ws;
    float* xs = ws;                            // N*128
    float* h1 = xs + (size_t)N * F_IN;         // N*256
    float* o1 = h1 + (size_t)N * HC1;          // N*256
    float* h2 = o1 + (size_t)N * HC1;          // N*160
    float* as1 = h2 + (size_t)N * HC2;         // N*4
    float* ad1 = as1 + (size_t)N * NHEAD;
    float* as2 = ad1 + (size_t)N * NHEAD;
    float* ad2 = as2 + (size_t)N * NHEAD;
    float* stats = ad2 + (size_t)N * NHEAD;    // 256
    int* counts = (int*)(stats + 256);         // N
    int* offsets = counts + N;                 // N+1 (pad 4)
    int* cursor = offsets + (N + 4);           // N
    int* csr = cursor + N;                     // E+N
    int* mode = csr + (E + N);                 // 1

    hipMemsetAsync(stats, 0, 256 * sizeof(float), stream);
    hipMemsetAsync(cursor, 0, (size_t)N * sizeof(int), stream);

    detect_mode_kernel<<<1, 256, 0, stream>>>((const unsigned int*)ei, 4096, mode);

    // standardize
    colstats_kernel<<<(N + 255) / 256, 256, 0, stream>>>(x, stats, N);
    finalize_stats_kernel<<<1, 128, 0, stream>>>(stats, N);
    long total = (long)N * F_IN;
    standardize_kernel<<<(int)((total + 255) / 256), 256, 0, stream>>>(x, stats, xs, total);

    // layer-1 transform + attention scores
    dim3 g1((HC1 + 63) / 64, (N + 63) / 64);
    sgemm_kernel<<<g1, 256, 0, stream>>>(xs, W1, h1, N, HC1, F_IN);
    att_kernel<<<N, 64, 0, stream>>>(h1, attS1, attD1, as1, ad1, C1);

    // CSR by dst (shared by both layers)
    init_counts_kernel<<<(N + 255) / 256, 256, 0, stream>>>(counts, N);
    count_kernel<<<(E + 255) / 256, 256, 0, stream>>>(ei, mode, E, counts);
    scan_kernel<<<1, 1024, 0, stream>>>(counts, offsets, N);
    fill_csr_kernel<<<(E + N + 255) / 256, 256, 0, stream>>>(ei, mode, E, N, offsets, cursor, csr);

    // layer-1 aggregate (+bias +ReLU)
    aggregate_kernel<HC1, C1, true><<<N, 256, 0, stream>>>(h1, as1, ad1, offsets, csr, b1, o1);

    // layer-2
    dim3 g2((HC2 + 63) / 64, (N + 63) / 64);
    sgemm_kernel<<<g2, 256, 0, stream>>>(o1, W2, h2, N, HC2, HC1);
    att_kernel<<<N, 64, 0, stream>>>(h2, attS2, attD2, as2, ad2, C2);
    aggregate_kernel<HC2, C2, false><<<N, 256, 0, stream>>>(h2, as2, ad2, offsets, csr, b2, out);
}

// Round 2
// 661.350 us; speedup vs baseline: 1.4038x; 1.4038x over previous
//
#include <hip/hip_runtime.h>
#include <hip/hip_fp16.h>
#include <math.h>

#define NEG_SLOPE 0.2f

constexpr int F_IN  = 128;
constexpr int HC1   = 256;  // H*HID
constexpr int C1    = 64;
constexpr int HC2   = 160;  // H*CLS
constexpr int C2    = 40;
constexpr int NHEAD = 4;

// ---------------- edge-index dtype hedge ----------------
__global__ void detect_mode_kernel(const unsigned int* __restrict__ p, int nwords, int* mode) {
    __shared__ unsigned int red[256];
    unsigned int v = 0;
    for (int i = 1 + 2 * (int)threadIdx.x; i < nwords; i += 512) v |= p[i];
    red[threadIdx.x] = v;
    __syncthreads();
    for (int off = 128; off > 0; off >>= 1) {
        if (threadIdx.x < off) red[threadIdx.x] |= red[threadIdx.x + off];
        __syncthreads();
    }
    if (threadIdx.x == 0) *mode = (red[0] == 0u) ? 1 : 0;
}

__device__ __forceinline__ int edge_val(const void* p, int m64, long long i) {
    if (m64) return (int)((const long long*)p)[i];
    return ((const int*)p)[i];
}

// ---------------- column stats (mean, 1/std ddof=1) ----------------
__global__ void colstats_kernel(const float* __restrict__ x, float* __restrict__ stats, int N) {
    int col = threadIdx.x & 127;
    int r0 = blockIdx.x * 256;
    int rend = min(r0 + 256, N);
    float s = 0.f, q = 0.f;
    for (int r = r0 + (int)(threadIdx.x >> 7); r < rend; r += 2) {
        float v = x[(long)r * F_IN + col];
        s += v;
        q += v * v;
    }
    __shared__ float sh[256];
    sh[threadIdx.x] = s;
    __syncthreads();
    if (threadIdx.x < 128) atomicAdd(&stats[col], sh[threadIdx.x] + sh[threadIdx.x + 128]);
    __syncthreads();
    sh[threadIdx.x] = q;
    __syncthreads();
    if (threadIdx.x < 128) atomicAdd(&stats[128 + col], sh[threadIdx.x] + sh[threadIdx.x + 128]);
}

__global__ void finalize_stats_kernel(float* stats, int N) {
    int c = threadIdx.x;  // 128
    float s = stats[c], q = stats[128 + c];
    float mean = s / (float)N;
    float var = (q - s * s / (float)N) / (float)(N - 1);
    stats[c] = mean;
    stats[128 + c] = 1.0f / sqrtf(var);
}

__global__ void standardize_kernel(const float* __restrict__ x, const float* __restrict__ stats,
                                   float* __restrict__ xs, long total) {
    long i = (long)blockIdx.x * blockDim.x + threadIdx.x;
    if (i >= total) return;
    int col = (int)(i & (F_IN - 1));
    xs[i] = (x[i] - stats[col]) * stats[128 + col];
}

// ---------------- tiled fp32 SGEMM: C = A[MxK] * B[KxN] ----------------
__global__ __launch_bounds__(256) void sgemm_kernel(const float* __restrict__ A,
                                                    const float* __restrict__ B,
                                                    float* __restrict__ C_,
                                                    int M, int N, int K) {
    __shared__ float As[16][68];
    __shared__ float Bs[16][64];
    int tid = threadIdx.x;
    int tx = tid & 15, ty = tid >> 4;
    int row0 = blockIdx.y * 64, col0 = blockIdx.x * 64;
    float acc[4][4] = {};

    for (int k0 = 0; k0 < K; k0 += 16) {
        {
            int l = tid * 4;
            int m = l >> 4;
            int kk = l & 15;
            int gr = row0 + m;
            float4 v = make_float4(0.f, 0.f, 0.f, 0.f);
            if (gr < M) v = *(const float4*)(A + (long)gr * K + k0 + kk);
            As[kk + 0][m] = v.x;
            As[kk + 1][m] = v.y;
            As[kk + 2][m] = v.z;
            As[kk + 3][m] = v.w;
        }
        {
            int l = tid * 4;
            int kk = l >> 6;
            int n = l & 63;
            int gc = col0 + n;
            float4 v = make_float4(0.f, 0.f, 0.f, 0.f);
            if (gc < N) v = *(const float4*)(B + (long)(k0 + kk) * N + gc);
            *(float4*)&Bs[kk][n] = v;
        }
        __syncthreads();
#pragma unroll
        for (int kk = 0; kk < 16; kk++) {
            float4 av = *(const float4*)&As[kk][ty * 4];
            float4 bv = *(const float4*)&Bs[kk][tx * 4];
            float a[4] = {av.x, av.y, av.z, av.w};
            float b[4] = {bv.x, bv.y, bv.z, bv.w};
#pragma unroll
            for (int i = 0; i < 4; i++)
#pragma unroll
                for (int j = 0; j < 4; j++) acc[i][j] += a[i] * b[j];
        }
        __syncthreads();
    }
#pragma unroll
    for (int i = 0; i < 4; i++) {
        int r = row0 + ty * 4 + i;
        if (r >= M) continue;
#pragma unroll
        for (int j = 0; j < 4; j++) {
            int c = col0 + tx * 4 + j;
            if (c < N) C_[(long)r * N + c] = acc[i][j];
        }
    }
}

// ---------------- attention scores + fp16 conversion of h ----------------
template <int HC, int C>
__global__ void att_kernel(const float* __restrict__ h, const float* __restrict__ att_s,
                           const float* __restrict__ att_d, float* __restrict__ as_,
                           float* __restrict__ ad_, __half* __restrict__ hb) {
    int node = blockIdx.x;
    int lane = threadIdx.x;  // 64
    const float* row = h + (long)node * HC;
    __half* hrow = hb + (long)node * HC;
#pragma unroll
    for (int hd = 0; hd < NHEAD; hd++) {
        float vs = 0.f, vd = 0.f;
        for (int c = lane; c < C; c += 64) {
            float v = row[hd * C + c];
            vs += v * att_s[hd * C + c];
            vd += v * att_d[hd * C + c];
        }
        for (int off = 32; off > 0; off >>= 1) {
            vs += __shfl_down(vs, off);
            vd += __shfl_down(vd, off);
        }
        if (lane == 0) {
            as_[node * NHEAD + hd] = vs;
            ad_[node * NHEAD + hd] = vd;
        }
    }
    for (int c = lane; c < HC; c += 64) hrow[c] = __float2half(row[c]);
}

// ---------------- CSR build over dst (self-loops via counts=1) ----------------
__global__ void init_counts_kernel(int* counts, int N) {
    int i = blockIdx.x * blockDim.x + threadIdx.x;
    if (i < N) counts[i] = 1;
}

__global__ void count_kernel(const void* __restrict__ ei, const int* __restrict__ mode, int E,
                             int* counts) {
    int e = blockIdx.x * blockDim.x + threadIdx.x;
    if (e >= E) return;
    int d = edge_val(ei, *mode, (long long)E + e);
    atomicAdd(&counts[d], 1);
}

// 3-kernel parallel exclusive scan: offsets[i+1] = inclusive prefix of counts
__global__ void scan_block_kernel(const int* __restrict__ counts, int* __restrict__ offsets,
                                  int* __restrict__ blocksum, int N) {
    int t = threadIdx.x;
    int i = blockIdx.x * 256 + t;
    int v = (i < N) ? counts[i] : 0;
    int lane = t & 63, w = t >> 6;
    int x = v;
#pragma unroll
    for (int d = 1; d < 64; d <<= 1) {
        int y = __shfl_up(x, d);
        if (lane >= d) x += y;
    }
    __shared__ int wsum[4];
    if (lane == 63) wsum[w] = x;
    __syncthreads();
    int base = 0;
    for (int k = 0; k < w; k++) base += wsum[k];
    int incl = x + base;
    if (i < N) offsets[i + 1] = incl;
    if (t == 255) blocksum[blockIdx.x] = incl;
}

__global__ void scan_top_kernel(int* blocksum, int nb) {
    int t = threadIdx.x;  // 256, nb <= 256
    int v = (t < nb) ? blocksum[t] : 0;
    int lane = t & 63, w = t >> 6;
    int x = v;
#pragma unroll
    for (int d = 1; d < 64; d <<= 1) {
        int y = __shfl_up(x, d);
        if (lane >= d) x += y;
    }
    __shared__ int wsum[4];
    if (lane == 63) wsum[w] = x;
    __syncthreads();
    int base = 0;
    for (int k = 0; k < w; k++) base += wsum[k];
    if (t < nb) blocksum[t] = x + base - v;  // exclusive base per block
}

__global__ void scan_add_kernel(const int* __restrict__ blocksum, int* __restrict__ offsets,
                                int N) {
    int i = blockIdx.x * 256 + threadIdx.x;
    if (i < N) offsets[i + 1] += blocksum[blockIdx.x];
    if (i == 0) offsets[0] = 0;
}

__global__ void fill_csr_kernel(const void* __restrict__ ei, const int* __restrict__ mode, int E,
                                int N, const int* __restrict__ offsets, int* cursor,
                                int* __restrict__ csr) {
    int e = blockIdx.x * blockDim.x + threadIdx.x;
    if (e >= E + N) return;
    int m = *mode;
    int s, d;
    if (e < E) {
        s = edge_val(ei, m, e);
        d = edge_val(ei, m, (long long)E + e);
    } else {
        s = d = e - E;
    }
    int pos = offsets[d] + atomicAdd(&cursor[d], 1);
    csr[pos] = s;
}

// ---------------- per-node softmax + aggregation ----------------
// Phase 1 stages per-edge src index + per-head exp weight in LDS (cap 512,
// with a fully correct global-recompute fallback). Phase 2 is a pure fp16
// weighted gather, unrolled x4 for memory-level parallelism.
template <int HC, int C, bool RELU>
__global__ __launch_bounds__(256) void aggregate_kernel(
    const __half* __restrict__ hb, const float* __restrict__ a_src,
    const float* __restrict__ a_dst, const int* __restrict__ offsets,
    const int* __restrict__ csr_src, const float* __restrict__ bias, float* __restrict__ out) {
    constexpr int CAP = 512;
    int node = blockIdx.x;
    int tid = threadIdx.x;  // 256
    int start = offsets[node], end = offsets[node + 1];
    int deg = end - start;
    __shared__ float ew[CAP * NHEAD];   // 8 KB
    __shared__ int sidx[CAP];           // 2 KB
    __shared__ float red[NHEAD * 256];  // 4 KB
    __shared__ float inv_s[NHEAD];

    float ad[NHEAD];
#pragma unroll
    for (int hd = 0; hd < NHEAD; hd++) ad[hd] = a_dst[node * NHEAD + hd];

    float ds[NHEAD] = {0.f, 0.f, 0.f, 0.f};
    if (deg <= CAP) {
        for (int i = start + tid; i < end; i += 256) {
            int j = i - start;
            int s = csr_src[i];
            sidx[j] = s;
            float4 av = ((const float4*)a_src)[s];
            float e0 = av.x + ad[0], e1 = av.y + ad[1], e2 = av.z + ad[2], e3 = av.w + ad[3];
            e0 = e0 > 0.f ? e0 : NEG_SLOPE * e0;
            e1 = e1 > 0.f ? e1 : NEG_SLOPE * e1;
            e2 = e2 > 0.f ? e2 : NEG_SLOPE * e2;
            e3 = e3 > 0.f ? e3 : NEG_SLOPE * e3;
            float w0 = __expf(e0), w1 = __expf(e1), w2 = __expf(e2), w3 = __expf(e3);
            ((float4*)ew)[j] = make_float4(w0, w1, w2, w3);
            ds[0] += w0;
            ds[1] += w1;
            ds[2] += w2;
            ds[3] += w3;
        }
    } else {
        for (int i = start + tid; i < end; i += 256) {
            int s = csr_src[i];
            float4 av = ((const float4*)a_src)[s];
            float ee[4] = {av.x, av.y, av.z, av.w};
#pragma unroll
            for (int hd = 0; hd < NHEAD; hd++) {
                float e = ee[hd] + ad[hd];
                e = e > 0.f ? e : NEG_SLOPE * e;
                ds[hd] += __expf(e);
            }
        }
    }
#pragma unroll
    for (int hd = 0; hd < NHEAD; hd++) red[hd * 256 + tid] = ds[hd];
    __syncthreads();
    for (int off = 128; off > 0; off >>= 1) {
        if (tid < off) {
#pragma unroll
            for (int hd = 0; hd < NHEAD; hd++) red[hd * 256 + tid] += red[hd * 256 + tid + off];
        }
        __syncthreads();
    }
    if (tid < NHEAD) inv_s[tid] = 1.0f / red[tid * 256];
    __syncthreads();

    if (tid < HC) {
        int hd = tid / C;
        const __half* hbase = hb + tid;
        float acc0 = 0.f, acc1 = 0.f, acc2 = 0.f, acc3 = 0.f;
        if (deg <= CAP) {
            int j = 0;
            for (; j + 4 <= deg; j += 4) {
                int s0 = sidx[j + 0], s1 = sidx[j + 1], s2 = sidx[j + 2], s3 = sidx[j + 3];
                float w0 = ew[(j + 0) * NHEAD + hd];
                float w1 = ew[(j + 1) * NHEAD + hd];
                float w2 = ew[(j + 2) * NHEAD + hd];
                float w3 = ew[(j + 3) * NHEAD + hd];
                acc0 += w0 * __half2float(hbase[(long)s0 * HC]);
                acc1 += w1 * __half2float(hbase[(long)s1 * HC]);
                acc2 += w2 * __half2float(hbase[(long)s2 * HC]);
                acc3 += w3 * __half2float(hbase[(long)s3 * HC]);
            }
            for (; j < deg; j++) {
                acc0 += ew[j * NHEAD + hd] * __half2float(hbase[(long)sidx[j] * HC]);
            }
        } else {
            float adh = ad[hd];
            for (int i = start; i < end; i++) {
                int s = csr_src[i];
                float e = a_src[s * NHEAD + hd] + adh;
                e = e > 0.f ? e : NEG_SLOPE * e;
                acc0 += __expf(e) * __half2float(hbase[(long)s * HC]);
            }
        }
        float r = (acc0 + acc1 + acc2 + acc3) * inv_s[hd] + bias[tid];
        if (RELU) r = fmaxf(r, 0.f);
        out[(long)node * HC + tid] = r;
    }
}

// ---------------- launch ----------------
extern "C" void kernel_launch(void* const* d_in, const int* in_sizes, int n_in, void* d_out,
                              int out_size, void* d_ws, size_t ws_size, hipStream_t stream) {
    const float* x = (const float*)d_in[0];
    const void* ei = d_in[1];
    const float* W1 = (const float*)d_in[2];
    const float* attS1 = (const float*)d_in[3];
    const float* attD1 = (const float*)d_in[4];
    const float* b1 = (const float*)d_in[5];
    const float* W2 = (const float*)d_in[6];
    const float* attS2 = (const float*)d_in[7];
    const float* attD2 = (const float*)d_in[8];
    const float* b2 = (const float*)d_in[9];
    float* out = (float*)d_out;

    int N = in_sizes[0] / F_IN;  // 50000
    int E = in_sizes[1] / 2;     // 800000
    int nb = (N + 255) / 256;

    // workspace layout (16B aligned). hb1 overlays xs (dead after sgemm1);
    // hb2 overlays o1 (dead after sgemm2). Stream-ordered, so safe.
    float* ws = (float*)d_ws;
    float* xs = ws;                            // N*128 f32  (later: hb1 = N*256 fp16)
    float* h1 = xs + (size_t)N * F_IN;         // N*256
    float* o1 = h1 + (size_t)N * HC1;          // N*256 f32  (later: hb2 = N*160 fp16)
    float* h2 = o1 + (size_t)N * HC1;          // N*160
    float* as1 = h2 + (size_t)N * HC2;         // N*4
    float* ad1 = as1 + (size_t)N * NHEAD;
    float* as2 = ad1 + (size_t)N * NHEAD;
    float* ad2 = as2 + (size_t)N * NHEAD;
    float* stats = ad2 + (size_t)N * NHEAD;    // 256
    int* counts = (int*)(stats + 256);         // N
    int* offsets = counts + N;                 // N+1 (pad 4)
    int* cursor = offsets + (N + 4);           // N
    int* csr = cursor + N;                     // E+N
    int* blocksum = csr + (E + N);             // 256
    int* mode = blocksum + 256;                // 1
    __half* hb1 = (__half*)xs;                 // N*256 fp16 == N*128 f32 bytes
    __half* hb2 = (__half*)o1;                 // N*160 fp16 < N*256 f32 bytes

    hipMemsetAsync(stats, 0, 256 * sizeof(float), stream);
    hipMemsetAsync(cursor, 0, (size_t)N * sizeof(int), stream);

    detect_mode_kernel<<<1, 256, 0, stream>>>((const unsigned int*)ei, 4096, mode);

    // standardize
    colstats_kernel<<<nb, 256, 0, stream>>>(x, stats, N);
    finalize_stats_kernel<<<1, 128, 0, stream>>>(stats, N);
    long total = (long)N * F_IN;
    standardize_kernel<<<(int)((total + 255) / 256), 256, 0, stream>>>(x, stats, xs, total);

    // CSR by dst (shared by both layers) — independent of GEMM, launch early
    init_counts_kernel<<<nb, 256, 0, stream>>>(counts, N);
    count_kernel<<<(E + 255) / 256, 256, 0, stream>>>(ei, mode, E, counts);
    scan_block_kernel<<<nb, 256, 0, stream>>>(counts, offsets, blocksum, N);
    scan_top_kernel<<<1, 256, 0, stream>>>(blocksum, nb);
    scan_add_kernel<<<nb, 256, 0, stream>>>(blocksum, offsets, N);
    fill_csr_kernel<<<(E + N + 255) / 256, 256, 0, stream>>>(ei, mode, E, N, offsets, cursor, csr);

    // layer-1 transform + attention scores (+h1 -> fp16)
    dim3 g1((HC1 + 63) / 64, (N + 63) / 64);
    sgemm_kernel<<<g1, 256, 0, stream>>>(xs, W1, h1, N, HC1, F_IN);
    att_kernel<HC1, C1><<<N, 64, 0, stream>>>(h1, attS1, attD1, as1, ad1, hb1);
    aggregate_kernel<HC1, C1, true><<<N, 256, 0, stream>>>(hb1, as1, ad1, offsets, csr, b1, o1);

    // layer-2
    dim3 g2((HC2 + 63) / 64, (N + 63) / 64);
    sgemm_kernel<<<g2, 256, 0, stream>>>(o1, W2, h2, N, HC2, HC1);
    att_kernel<HC2, C2><<<N, 64, 0, stream>>>(h2, attS2, attD2, as2, ad2, hb2);
    aggregate_kernel<HC2, C2, false><<<N, 256, 0, stream>>>(hb2, as2, ad2, offsets, csr, b2, out);
}

// Round 3
// 555.935 us; speedup vs baseline: 1.6700x; 1.1896x over previous
//
#include <hip/hip_runtime.h>
#include <math.h>

#define NEG_SLOPE 0.2f

constexpr int F_IN  = 128;
constexpr int HC1   = 256;  // H*HID
constexpr int HC2   = 160;  // H*CLS
constexpr int NHEAD = 4;

typedef _Float16 h8v __attribute__((ext_vector_type(8)));
typedef _Float16 h4v __attribute__((ext_vector_type(4)));
typedef float f4v __attribute__((ext_vector_type(4)));

// ---------------- edge-index dtype hedge ----------------
__global__ void detect_mode_kernel(const unsigned int* __restrict__ p, int nwords, int* mode) {
    __shared__ unsigned int red[256];
    unsigned int v = 0;
    for (int i = 1 + 2 * (int)threadIdx.x; i < nwords; i += 512) v |= p[i];
    red[threadIdx.x] = v;
    __syncthreads();
    for (int off = 128; off > 0; off >>= 1) {
        if (threadIdx.x < off) red[threadIdx.x] |= red[threadIdx.x + off];
        __syncthreads();
    }
    if (threadIdx.x == 0) *mode = (red[0] == 0u) ? 1 : 0;
}

__device__ __forceinline__ int edge_val(const void* p, int m64, long long i) {
    if (m64) return (int)((const long long*)p)[i];
    return ((const int*)p)[i];
}

// ---------------- column stats (mean, 1/std ddof=1) ----------------
__global__ void colstats_kernel(const float* __restrict__ x, float* __restrict__ stats, int N) {
    int col = threadIdx.x & 127;
    int r0 = blockIdx.x * 256;
    int rend = min(r0 + 256, N);
    float s = 0.f, q = 0.f;
    for (int r = r0 + (int)(threadIdx.x >> 7); r < rend; r += 2) {
        float v = x[(long)r * F_IN + col];
        s += v;
        q += v * v;
    }
    __shared__ float sh[256];
    sh[threadIdx.x] = s;
    __syncthreads();
    if (threadIdx.x < 128) atomicAdd(&stats[col], sh[threadIdx.x] + sh[threadIdx.x + 128]);
    __syncthreads();
    sh[threadIdx.x] = q;
    __syncthreads();
    if (threadIdx.x < 128) atomicAdd(&stats[128 + col], sh[threadIdx.x] + sh[threadIdx.x + 128]);
}

__global__ void finalize_stats_kernel(float* stats, int N) {
    int c = threadIdx.x;  // 128
    float s = stats[c], q = stats[128 + c];
    float mean = s / (float)N;
    float var = (q - s * s / (float)N) / (float)(N - 1);
    stats[c] = mean;
    stats[128 + c] = 1.0f / sqrtf(var);
}

// standardize + convert to fp16, 4 elems/thread
__global__ void standardize_kernel(const float* __restrict__ x, const float* __restrict__ stats,
                                   _Float16* __restrict__ xs, int total4) {
    int i = blockIdx.x * blockDim.x + threadIdx.x;
    if (i >= total4) return;
    float4 v = ((const float4*)x)[i];
    int c = (i * 4) & (F_IN - 1);
    h4v o;
    o[0] = (_Float16)((v.x - stats[c + 0]) * stats[128 + c + 0]);
    o[1] = (_Float16)((v.y - stats[c + 1]) * stats[128 + c + 1]);
    o[2] = (_Float16)((v.z - stats[c + 2]) * stats[128 + c + 2]);
    o[3] = (_Float16)((v.w - stats[c + 3]) * stats[128 + c + 3]);
    ((h4v*)xs)[i] = o;
}

// ---------------- weight transpose + fp16 convert: W[K][Nc] -> Wt[Nc][K] ----------------
__global__ void convert_w_kernel(const float* __restrict__ W, _Float16* __restrict__ Wt, int K,
                                 int Nc) {
    int idx = blockIdx.x * blockDim.x + threadIdx.x;
    if (idx >= K * Nc) return;
    int k = idx / Nc, n = idx - k * Nc;
    Wt[(long)n * K + k] = (_Float16)W[idx];
}

// ---------------- MFMA f16 GEMM: C[M][Nc] = A[M][K] * Bt[Nc][K]^T ----------------
// mfma_f32_16x16x32_f16 layouts (verified m89/m91/m120):
//   A-frag: lane holds A[m=lane&15][k=(lane>>4)*8 + j], j=0..7
//   B-frag: lane holds B[k=(lane>>4)*8 + j][n=lane&15]
//   D:      lane holds D[row=(lane>>4)*4 + r][col=lane&15], r=0..3
template <int Nc, int K>
__global__ __launch_bounds__(256) void gemm_f16_kernel(const _Float16* __restrict__ A,
                                                       const _Float16* __restrict__ Bt,
                                                       _Float16* __restrict__ C_, int M) {
    constexpr int NT = Nc / 16;
    constexpr int KT = K / 32;
    int w = threadIdx.x >> 6;
    int l = threadIdx.x & 63;
    int quad = l >> 4, lan = l & 15;
    int row = blockIdx.x * 64 + w * 16 + lan;
    int arow = min(row, M - 1);
    f4v acc[NT] = {};
    const _Float16* Aptr = A + (long)arow * K + quad * 8;
#pragma unroll
    for (int k0 = 0; k0 < KT; k0++) {
        h8v af = *(const h8v*)(Aptr + k0 * 32);
#pragma unroll
        for (int ct = 0; ct < NT; ct++) {
            const _Float16* Bptr = Bt + (long)(ct * 16 + lan) * K + k0 * 32 + quad * 8;
            h8v bf = *(const h8v*)Bptr;
            acc[ct] = __builtin_amdgcn_mfma_f32_16x16x32_f16(af, bf, acc[ct], 0, 0, 0);
        }
    }
    int orow = blockIdx.x * 64 + w * 16 + quad * 4;
#pragma unroll
    for (int r = 0; r < 4; r++) {
        int gr = orow + r;
        if (gr < M) {
            _Float16* out = C_ + (long)gr * Nc + lan;
#pragma unroll
            for (int ct = 0; ct < NT; ct++) out[ct * 16] = (_Float16)acc[ct][r];
        }
    }
}

// ---------------- attention scores from fp16 h ----------------
template <int HC, int C>
__global__ void att_kernel(const _Float16* __restrict__ hb, const float* __restrict__ att_s,
                           const float* __restrict__ att_d, float* __restrict__ as_,
                           float* __restrict__ ad_) {
    int node = blockIdx.x;
    int lane = threadIdx.x;  // 64
    const _Float16* row = hb + (long)node * HC;
#pragma unroll
    for (int hd = 0; hd < NHEAD; hd++) {
        float vs = 0.f, vd = 0.f;
        for (int c = lane; c < C; c += 64) {
            float v = (float)row[hd * C + c];
            vs += v * att_s[hd * C + c];
            vd += v * att_d[hd * C + c];
        }
        for (int off = 32; off > 0; off >>= 1) {
            vs += __shfl_down(vs, off);
            vd += __shfl_down(vd, off);
        }
        if (lane == 0) {
            as_[node * NHEAD + hd] = vs;
            ad_[node * NHEAD + hd] = vd;
        }
    }
}

// ---------------- CSR build over dst (self-loops via counts=1) ----------------
__global__ void init_counts_kernel(int* counts, int N) {
    int i = blockIdx.x * blockDim.x + threadIdx.x;
    if (i < N) counts[i] = 1;
}

__global__ void count_kernel(const void* __restrict__ ei, const int* __restrict__ mode, int E,
                             int* counts) {
    int e = blockIdx.x * blockDim.x + threadIdx.x;
    if (e >= E) return;
    int d = edge_val(ei, *mode, (long long)E + e);
    atomicAdd(&counts[d], 1);
}

__global__ void scan_block_kernel(const int* __restrict__ counts, int* __restrict__ offsets,
                                  int* __restrict__ blocksum, int N) {
    int t = threadIdx.x;
    int i = blockIdx.x * 256 + t;
    int v = (i < N) ? counts[i] : 0;
    int lane = t & 63, w = t >> 6;
    int x = v;
#pragma unroll
    for (int d = 1; d < 64; d <<= 1) {
        int y = __shfl_up(x, d);
        if (lane >= d) x += y;
    }
    __shared__ int wsum[4];
    if (lane == 63) wsum[w] = x;
    __syncthreads();
    int base = 0;
    for (int k = 0; k < w; k++) base += wsum[k];
    int incl = x + base;
    if (i < N) offsets[i + 1] = incl;
    if (t == 255) blocksum[blockIdx.x] = incl;
}

__global__ void scan_top_kernel(int* blocksum, int nb) {
    int t = threadIdx.x;  // 256, nb <= 256
    int v = (t < nb) ? blocksum[t] : 0;
    int lane = t & 63, w = t >> 6;
    int x = v;
#pragma unroll
    for (int d = 1; d < 64; d <<= 1) {
        int y = __shfl_up(x, d);
        if (lane >= d) x += y;
    }
    __shared__ int wsum[4];
    if (lane == 63) wsum[w] = x;
    __syncthreads();
    int base = 0;
    for (int k = 0; k < w; k++) base += wsum[k];
    if (t < nb) blocksum[t] = x + base - v;
}

__global__ void scan_add_kernel(const int* __restrict__ blocksum, int* __restrict__ offsets,
                                int N) {
    int i = blockIdx.x * 256 + threadIdx.x;
    if (i < N) offsets[i + 1] += blocksum[blockIdx.x];
    if (i == 0) offsets[0] = 0;
}

__global__ void fill_csr_kernel(const void* __restrict__ ei, const int* __restrict__ mode, int E,
                                int N, const int* __restrict__ offsets, int* cursor,
                                int* __restrict__ csr) {
    int e = blockIdx.x * blockDim.x + threadIdx.x;
    if (e >= E + N) return;
    int m = *mode;
    int s, d;
    if (e < E) {
        s = edge_val(ei, m, e);
        d = edge_val(ei, m, (long long)E + e);
    } else {
        s = d = e - E;
    }
    int pos = offsets[d] + atomicAdd(&cursor[d], 1);
    csr[pos] = s;
}

// ---------------- per-node softmax + aggregation ----------------
// Phase 1: stage per-edge src idx + per-head exp weight in LDS; denom via shfl.
// Phase 2: wave-per-edge whole-row fp16 gather (4 ch/lane), 4 edges in flight.
template <int HC, bool RELU, typename OutT>
__global__ __launch_bounds__(256) void aggregate_kernel(
    const _Float16* __restrict__ hb, const float* __restrict__ a_src,
    const float* __restrict__ a_dst, const int* __restrict__ offsets,
    const int* __restrict__ csr_src, const float* __restrict__ bias, OutT* __restrict__ out) {
    constexpr int CAP = 512;
    constexpr int ACT = HC / 4;        // active gather lanes (64 or 40)
    constexpr int CH = HC / NHEAD;     // channels per head (64 or 40)
    int node = blockIdx.x;
    int tid = threadIdx.x;  // 256
    int w = tid >> 6, l = tid & 63;
    int start = offsets[node], end = offsets[node + 1];
    int deg = end - start;

    __shared__ int sidx[CAP];           // 2 KB
    __shared__ float ew[CAP * NHEAD];   // 8 KB
    __shared__ float dsum[4][NHEAD];
    __shared__ float inv_s[NHEAD];
    __shared__ float redf[4][HC];       // 4 / 2.5 KB

    float4 adv = ((const float4*)a_dst)[node];

    float ds0 = 0.f, ds1 = 0.f, ds2 = 0.f, ds3 = 0.f;
    if (deg <= CAP) {
        for (int i = start + tid; i < end; i += 256) {
            int j = i - start;
            int s = csr_src[i];
            sidx[j] = s;
            float4 av = ((const float4*)a_src)[s];
            float e0 = av.x + adv.x, e1 = av.y + adv.y, e2 = av.z + adv.z, e3 = av.w + adv.w;
            e0 = e0 > 0.f ? e0 : NEG_SLOPE * e0;
            e1 = e1 > 0.f ? e1 : NEG_SLOPE * e1;
            e2 = e2 > 0.f ? e2 : NEG_SLOPE * e2;
            e3 = e3 > 0.f ? e3 : NEG_SLOPE * e3;
            float w0 = __expf(e0), w1 = __expf(e1), w2 = __expf(e2), w3 = __expf(e3);
            ((float4*)ew)[j] = make_float4(w0, w1, w2, w3);
            ds0 += w0;
            ds1 += w1;
            ds2 += w2;
            ds3 += w3;
        }
    } else {
        for (int i = start + tid; i < end; i += 256) {
            int s = csr_src[i];
            float4 av = ((const float4*)a_src)[s];
            float e0 = av.x + adv.x, e1 = av.y + adv.y, e2 = av.z + adv.z, e3 = av.w + adv.w;
            e0 = e0 > 0.f ? e0 : NEG_SLOPE * e0;
            e1 = e1 > 0.f ? e1 : NEG_SLOPE * e1;
            e2 = e2 > 0.f ? e2 : NEG_SLOPE * e2;
            e3 = e3 > 0.f ? e3 : NEG_SLOPE * e3;
            ds0 += __expf(e0);
            ds1 += __expf(e1);
            ds2 += __expf(e2);
            ds3 += __expf(e3);
        }
    }
#pragma unroll
    for (int off = 1; off < 64; off <<= 1) {
        ds0 += __shfl_xor(ds0, off);
        ds1 += __shfl_xor(ds1, off);
        ds2 += __shfl_xor(ds2, off);
        ds3 += __shfl_xor(ds3, off);
    }
    if (l == 0) {
        dsum[w][0] = ds0;
        dsum[w][1] = ds1;
        dsum[w][2] = ds2;
        dsum[w][3] = ds3;
    }
    __syncthreads();
    if (tid < NHEAD)
        inv_s[tid] = 1.0f / (dsum[0][tid] + dsum[1][tid] + dsum[2][tid] + dsum[3][tid]);

    // phase 2: wave w handles edges w, w+4, ...; lane covers 4 channels
    float a0 = 0.f, a1 = 0.f, a2 = 0.f, a3 = 0.f;
    if (l < ACT) {
        const int hd = (4 * l) / CH;
        const _Float16* hbase = hb + 4 * l;
        if (deg <= CAP) {
            int j = w;
            for (; j + 4 < deg; j += 8) {
                int s0 = sidx[j], s1 = sidx[j + 4];
                float w0 = ew[j * 4 + hd], w1 = ew[(j + 4) * 4 + hd];
                h4v v0 = *(const h4v*)(hbase + (long)s0 * HC);
                h4v v1 = *(const h4v*)(hbase + (long)s1 * HC);
                a0 += w0 * (float)v0[0];
                a1 += w0 * (float)v0[1];
                a2 += w0 * (float)v0[2];
                a3 += w0 * (float)v0[3];
                a0 += w1 * (float)v1[0];
                a1 += w1 * (float)v1[1];
                a2 += w1 * (float)v1[2];
                a3 += w1 * (float)v1[3];
            }
            if (j < deg) {
                int s0 = sidx[j];
                float w0 = ew[j * 4 + hd];
                h4v v0 = *(const h4v*)(hbase + (long)s0 * HC);
                a0 += w0 * (float)v0[0];
                a1 += w0 * (float)v0[1];
                a2 += w0 * (float)v0[2];
                a3 += w0 * (float)v0[3];
            }
        } else {
            float adh = hd == 0 ? adv.x : hd == 1 ? adv.y : hd == 2 ? adv.z : adv.w;
            for (int j = w; j < deg; j += 4) {
                int s = csr_src[start + j];
                float4 av = ((const float4*)a_src)[s];
                float e = hd == 0 ? av.x : hd == 1 ? av.y : hd == 2 ? av.z : av.w;
                e += adh;
                e = e > 0.f ? e : NEG_SLOPE * e;
                float w0 = __expf(e);
                h4v v0 = *(const h4v*)(hbase + (long)s * HC);
                a0 += w0 * (float)v0[0];
                a1 += w0 * (float)v0[1];
                a2 += w0 * (float)v0[2];
                a3 += w0 * (float)v0[3];
            }
        }
        *(float4*)&redf[w][4 * l] = make_float4(a0, a1, a2, a3);
    }
    __syncthreads();

    if (tid < HC) {
        int hd2 = tid / CH;
        float r = (redf[0][tid] + redf[1][tid] + redf[2][tid] + redf[3][tid]) * inv_s[hd2] +
                  bias[tid];
        if (RELU) r = fmaxf(r, 0.f);
        out[(long)node * HC + tid] = (OutT)r;
    }
}

// ---------------- launch ----------------
extern "C" void kernel_launch(void* const* d_in, const int* in_sizes, int n_in, void* d_out,
                              int out_size, void* d_ws, size_t ws_size, hipStream_t stream) {
    const float* x = (const float*)d_in[0];
    const void* ei = d_in[1];
    const float* W1 = (const float*)d_in[2];
    const float* attS1 = (const float*)d_in[3];
    const float* attD1 = (const float*)d_in[4];
    const float* b1 = (const float*)d_in[5];
    const float* W2 = (const float*)d_in[6];
    const float* attS2 = (const float*)d_in[7];
    const float* attD2 = (const float*)d_in[8];
    const float* b2 = (const float*)d_in[9];
    float* out = (float*)d_out;

    int N = in_sizes[0] / F_IN;  // 50000
    int E = in_sizes[1] / 2;     // 800000
    int nb = (N + 255) / 256;

    // workspace layout (all 16B aligned)
    _Float16* xs_h = (_Float16*)d_ws;           // N*128
    _Float16* hb1 = xs_h + (size_t)N * F_IN;    // N*256
    _Float16* o1h = hb1 + (size_t)N * HC1;      // N*256
    _Float16* hb2 = o1h + (size_t)N * HC1;      // N*160
    _Float16* W1t = hb2 + (size_t)N * HC2;      // 256*128
    _Float16* W2t = W1t + HC1 * F_IN;           // 160*256
    float* as1 = (float*)(W2t + HC2 * HC1);     // N*4 each
    float* ad1 = as1 + (size_t)N * NHEAD;
    float* as2 = ad1 + (size_t)N * NHEAD;
    float* ad2 = as2 + (size_t)N * NHEAD;
    float* stats = ad2 + (size_t)N * NHEAD;     // 256
    int* counts = (int*)(stats + 256);          // N
    int* offsets = counts + N;                  // N+1 (pad 4)
    int* cursor = offsets + (N + 4);            // N
    int* csr = cursor + N;                      // E+N
    int* blocksum = csr + (E + N);              // 256
    int* mode = blocksum + 256;                 // 1

    hipMemsetAsync(stats, 0, 256 * sizeof(float), stream);
    hipMemsetAsync(cursor, 0, (size_t)N * sizeof(int), stream);

    detect_mode_kernel<<<1, 256, 0, stream>>>((const unsigned int*)ei, 4096, mode);

    // standardize -> fp16
    colstats_kernel<<<nb, 256, 0, stream>>>(x, stats, N);
    finalize_stats_kernel<<<1, 128, 0, stream>>>(stats, N);
    int total4 = N * F_IN / 4;
    standardize_kernel<<<(total4 + 255) / 256, 256, 0, stream>>>(x, stats, xs_h, total4);

    // weights -> fp16 transposed
    convert_w_kernel<<<(F_IN * HC1 + 255) / 256, 256, 0, stream>>>(W1, W1t, F_IN, HC1);
    convert_w_kernel<<<(HC1 * HC2 + 255) / 256, 256, 0, stream>>>(W2, W2t, HC1, HC2);

    // CSR by dst (shared by both layers)
    init_counts_kernel<<<nb, 256, 0, stream>>>(counts, N);
    count_kernel<<<(E + 255) / 256, 256, 0, stream>>>(ei, mode, E, counts);
    scan_block_kernel<<<nb, 256, 0, stream>>>(counts, offsets, blocksum, N);
    scan_top_kernel<<<1, 256, 0, stream>>>(blocksum, nb);
    scan_add_kernel<<<nb, 256, 0, stream>>>(blocksum, offsets, N);
    fill_csr_kernel<<<(E + N + 255) / 256, 256, 0, stream>>>(ei, mode, E, N, offsets, cursor, csr);

    // layer 1
    gemm_f16_kernel<HC1, F_IN><<<(N + 63) / 64, 256, 0, stream>>>(xs_h, W1t, hb1, N);
    att_kernel<HC1, HC1 / NHEAD><<<N, 64, 0, stream>>>(hb1, attS1, attD1, as1, ad1);
    aggregate_kernel<HC1, true, _Float16>
        <<<N, 256, 0, stream>>>(hb1, as1, ad1, offsets, csr, b1, o1h);

    // layer 2
    gemm_f16_kernel<HC2, HC1><<<(N + 63) / 64, 256, 0, stream>>>(o1h, W2t, hb2, N);
    att_kernel<HC2, HC2 / NHEAD><<<N, 64, 0, stream>>>(hb2, attS2, attD2, as2, ad2);
    aggregate_kernel<HC2, false, float>
        <<<N, 256, 0, stream>>>(hb2, as2, ad2, offsets, csr, b2, out);
}

// Round 4
// 451.288 us; speedup vs baseline: 2.0573x; 1.2319x over previous
//
#include <hip/hip_runtime.h>
#include <math.h>

#define NEG_SLOPE 0.2f

constexpr int F_IN  = 128;
constexpr int HC1   = 256;  // H*HID
constexpr int HC2   = 160;  // H*CLS
constexpr int NHEAD = 4;

typedef _Float16 h8v __attribute__((ext_vector_type(8)));
typedef _Float16 h4v __attribute__((ext_vector_type(4)));
typedef float f4v __attribute__((ext_vector_type(4)));

// ---------------- edge-index dtype hedge ----------------
__global__ void detect_mode_kernel(const unsigned int* __restrict__ p, int nwords, int* mode) {
    __shared__ unsigned int red[256];
    unsigned int v = 0;
    for (int i = 1 + 2 * (int)threadIdx.x; i < nwords; i += 512) v |= p[i];
    red[threadIdx.x] = v;
    __syncthreads();
    for (int off = 128; off > 0; off >>= 1) {
        if (threadIdx.x < off) red[threadIdx.x] |= red[threadIdx.x + off];
        __syncthreads();
    }
    if (threadIdx.x == 0) *mode = (red[0] == 0u) ? 1 : 0;
}

__device__ __forceinline__ int edge_val(const void* p, int m64, long long i) {
    if (m64) return (int)((const long long*)p)[i];
    return ((const int*)p)[i];
}

// ---------------- column stats (mean, 1/std ddof=1) ----------------
__global__ void colstats_kernel(const float* __restrict__ x, float* __restrict__ stats, int N) {
    int col = threadIdx.x & 127;
    int r0 = blockIdx.x * 256;
    int rend = min(r0 + 256, N);
    float s = 0.f, q = 0.f;
    for (int r = r0 + (int)(threadIdx.x >> 7); r < rend; r += 2) {
        float v = x[(long)r * F_IN + col];
        s += v;
        q += v * v;
    }
    __shared__ float sh[256];
    sh[threadIdx.x] = s;
    __syncthreads();
    if (threadIdx.x < 128) atomicAdd(&stats[col], sh[threadIdx.x] + sh[threadIdx.x + 128]);
    __syncthreads();
    sh[threadIdx.x] = q;
    __syncthreads();
    if (threadIdx.x < 128) atomicAdd(&stats[128 + col], sh[threadIdx.x] + sh[threadIdx.x + 128]);
}

__global__ void finalize_stats_kernel(float* stats, int N) {
    int c = threadIdx.x;  // 128
    float s = stats[c], q = stats[128 + c];
    float mean = s / (float)N;
    float var = (q - s * s / (float)N) / (float)(N - 1);
    stats[c] = mean;
    stats[128 + c] = 1.0f / sqrtf(var);
}

// standardize + convert to fp16, 4 elems/thread
__global__ void standardize_kernel(const float* __restrict__ x, const float* __restrict__ stats,
                                   _Float16* __restrict__ xs, int total4) {
    int i = blockIdx.x * blockDim.x + threadIdx.x;
    if (i >= total4) return;
    float4 v = ((const float4*)x)[i];
    int c = (i * 4) & (F_IN - 1);
    h4v o;
    o[0] = (_Float16)((v.x - stats[c + 0]) * stats[128 + c + 0]);
    o[1] = (_Float16)((v.y - stats[c + 1]) * stats[128 + c + 1]);
    o[2] = (_Float16)((v.z - stats[c + 2]) * stats[128 + c + 2]);
    o[3] = (_Float16)((v.w - stats[c + 3]) * stats[128 + c + 3]);
    ((h4v*)xs)[i] = o;
}

// ---------------- both weight transposes + fp16 convert in one dispatch ----------------
__global__ void convert_w_kernel(const float* __restrict__ W1, _Float16* __restrict__ W1t,
                                 const float* __restrict__ W2, _Float16* __restrict__ W2t) {
    int idx = blockIdx.x * blockDim.x + threadIdx.x;
    if (idx < F_IN * HC1) {
        int k = idx / HC1, n = idx - k * HC1;
        W1t[n * F_IN + k] = (_Float16)W1[idx];
    } else if (idx < F_IN * HC1 + HC1 * HC2) {
        int i2 = idx - F_IN * HC1;
        int k = i2 / HC2, n = i2 - k * HC2;
        W2t[n * HC1 + k] = (_Float16)W2[i2];
    }
}

// ---------------- MFMA f16 GEMM: C[M][Nc] = A[M][K] * Bt[Nc][K]^T ----------------
// mfma_f32_16x16x32_f16: A-frag lane holds A[m=lane&15][k=(lane>>4)*8+j];
// B mirrored; D lane holds D[row=(lane>>4)*4+r][col=lane&15].
template <int Nc, int K>
__global__ __launch_bounds__(256) void gemm_f16_kernel(const _Float16* __restrict__ A,
                                                       const _Float16* __restrict__ Bt,
                                                       _Float16* __restrict__ C_, int M) {
    constexpr int NT = Nc / 16;
    constexpr int KT = K / 32;
    int w = threadIdx.x >> 6;
    int l = threadIdx.x & 63;
    int quad = l >> 4, lan = l & 15;
    int row = blockIdx.x * 64 + w * 16 + lan;
    int arow = min(row, M - 1);
    f4v acc[NT] = {};
    const _Float16* Aptr = A + (long)arow * K + quad * 8;
#pragma unroll
    for (int k0 = 0; k0 < KT; k0++) {
        h8v af = *(const h8v*)(Aptr + k0 * 32);
#pragma unroll
        for (int ct = 0; ct < NT; ct++) {
            const _Float16* Bptr = Bt + (long)(ct * 16 + lan) * K + k0 * 32 + quad * 8;
            h8v bf = *(const h8v*)Bptr;
            acc[ct] = __builtin_amdgcn_mfma_f32_16x16x32_f16(af, bf, acc[ct], 0, 0, 0);
        }
    }
    int orow = blockIdx.x * 64 + w * 16 + quad * 4;
#pragma unroll
    for (int r = 0; r < 4; r++) {
        int gr = orow + r;
        if (gr < M) {
            _Float16* out = C_ + (long)gr * Nc + lan;
#pragma unroll
            for (int ct = 0; ct < NT; ct++) out[ct * 16] = (_Float16)acc[ct][r];
        }
    }
}

// ---------------- attention scores: one wave per node ----------------
template <int HC>
__global__ __launch_bounds__(256) void att_kernel(const _Float16* __restrict__ hb,
                                                  const float* __restrict__ att_s,
                                                  const float* __restrict__ att_d,
                                                  float* __restrict__ as_, float* __restrict__ ad_,
                                                  int Ntot) {
    constexpr int ACT = HC / 4;
    int w = threadIdx.x >> 6, l = threadIdx.x & 63;
    int node = blockIdx.x * 4 + w;
    if (node >= Ntot) return;  // node is wave-uniform: whole wave exits
    float vs = 0.f, vd = 0.f;
    if (l < ACT) {
        h4v hv = *(const h4v*)(hb + (long)node * HC + 4 * l);
        float4 s4 = ((const float4*)att_s)[l];
        float4 d4 = ((const float4*)att_d)[l];
        float h0 = (float)hv[0], h1 = (float)hv[1], h2 = (float)hv[2], h3 = (float)hv[3];
        vs = h0 * s4.x + h1 * s4.y + h2 * s4.z + h3 * s4.w;
        vd = h0 * d4.x + h1 * d4.y + h2 * d4.z + h3 * d4.w;
    }
    if (HC == 256) {
        // heads are groups of 16 lanes
#pragma unroll
        for (int off = 1; off < 16; off <<= 1) {
            vs += __shfl_xor(vs, off);
            vd += __shfl_xor(vd, off);
        }
        if ((l & 15) == 0) {
            as_[node * NHEAD + (l >> 4)] = vs;
            ad_[node * NHEAD + (l >> 4)] = vd;
        }
    } else {
        // HC=160: heads are groups of 10 lanes; per-wave LDS scratch, no barrier
        __shared__ float sv[4][64], sd_[4][64];
        sv[w][l] = vs;
        sd_[w][l] = vd;
        if (l < 8) {
            int hd = l & 3;
            bool doS = l < 4;
            float t = 0.f;
#pragma unroll
            for (int k = 0; k < 10; k++) t += doS ? sv[w][hd * 10 + k] : sd_[w][hd * 10 + k];
            if (doS)
                as_[node * NHEAD + hd] = t;
            else
                ad_[node * NHEAD + hd] = t;
        }
    }
}

// ---------------- CSR build over dst ----------------
__global__ void count_kernel(const void* __restrict__ ei, const int* __restrict__ mode, int E,
                             int* counts) {
    int e = blockIdx.x * blockDim.x + threadIdx.x;
    if (e >= E) return;
    int d = edge_val(ei, *mode, (long long)E + e);
    atomicAdd(&counts[d], 1);
}

// self-loop (+1 per node) folded in here
__global__ void scan_block_kernel(const int* __restrict__ counts, int* __restrict__ offsets,
                                  int* __restrict__ blocksum, int N) {
    int t = threadIdx.x;
    int i = blockIdx.x * 256 + t;
    int v = (i < N) ? counts[i] + 1 : 0;
    int lane = t & 63, w = t >> 6;
    int x = v;
#pragma unroll
    for (int d = 1; d < 64; d <<= 1) {
        int y = __shfl_up(x, d);
        if (lane >= d) x += y;
    }
    __shared__ int wsum[4];
    if (lane == 63) wsum[w] = x;
    __syncthreads();
    int base = 0;
    for (int k = 0; k < w; k++) base += wsum[k];
    int incl = x + base;
    if (i < N) offsets[i + 1] = incl;
    if (t == 255) blocksum[blockIdx.x] = incl;
}

__global__ void scan_top_kernel(int* blocksum, int nb) {
    int t = threadIdx.x;  // 256, nb <= 256
    int v = (t < nb) ? blocksum[t] : 0;
    int lane = t & 63, w = t >> 6;
    int x = v;
#pragma unroll
    for (int d = 1; d < 64; d <<= 1) {
        int y = __shfl_up(x, d);
        if (lane >= d) x += y;
    }
    __shared__ int wsum[4];
    if (lane == 63) wsum[w] = x;
    __syncthreads();
    int base = 0;
    for (int k = 0; k < w; k++) base += wsum[k];
    if (t < nb) blocksum[t] = x + base - v;
}

__global__ void scan_add_kernel(const int* __restrict__ blocksum, int* __restrict__ offsets,
                                int N) {
    int i = blockIdx.x * 256 + threadIdx.x;
    if (i < N) offsets[i + 1] += blocksum[blockIdx.x];
    if (i == 0) offsets[0] = 0;
}

__global__ void fill_csr_kernel(const void* __restrict__ ei, const int* __restrict__ mode, int E,
                                int N, const int* __restrict__ offsets, int* cursor,
                                int* __restrict__ csr) {
    int e = blockIdx.x * blockDim.x + threadIdx.x;
    if (e >= E + N) return;
    int m = *mode;
    int s, d;
    if (e < E) {
        s = edge_val(ei, m, e);
        d = edge_val(ei, m, (long long)E + e);
    } else {
        s = d = e - E;
    }
    int pos = offsets[d] + atomicAdd(&cursor[d], 1);
    csr[pos] = s;
}

// ---------------- softmax + aggregation: one wave per node, zero barriers ----------------
// Phase 1 (per 64-edge chunk): lane computes exp-weights for one edge, stages
// src idx + 4 head weights in this wave's LDS strip (same-wave DS order, no
// __syncthreads). Phase 2: lane covers 4 channels, whole-row fp16 gather,
// unrolled x4 for 4 loads in flight.
template <int HC, bool RELU, typename OutT>
__global__ __launch_bounds__(256) void aggregate_kernel(
    const _Float16* __restrict__ hb, const float* __restrict__ a_src,
    const float* __restrict__ a_dst, const int* __restrict__ offsets,
    const int* __restrict__ csr_src, const float* __restrict__ bias, OutT* __restrict__ out,
    int Ntot) {
    constexpr int ACT = HC / 4;        // active gather lanes (64 or 40)
    constexpr int CHPH = HC / NHEAD;   // channels per head
    int w = threadIdx.x >> 6, l = threadIdx.x & 63;
    int node = blockIdx.x * 4 + w;
    if (node >= Ntot) return;  // wave-uniform exit

    __shared__ int sidx_sh[4][64];
    __shared__ float ew_sh[4][64][4];

    int start = offsets[node], end = offsets[node + 1];
    int deg = end - start;
    float4 adv = ((const float4*)a_dst)[node];
    const int hd = (4 * l) / CHPH;  // head of this lane's channels (valid for l < ACT)
    const _Float16* hbase = hb + 4 * l;

    float ds0 = 0.f, ds1 = 0.f, ds2 = 0.f, ds3 = 0.f;
    float a0 = 0.f, a1 = 0.f, a2 = 0.f, a3 = 0.f;

    for (int base = 0; base < deg; base += 64) {
        int cnt = min(64, deg - base);
        if (l < cnt) {
            int s = csr_src[start + base + l];
            sidx_sh[w][l] = s;
            float4 av = ((const float4*)a_src)[s];
            float e0 = av.x + adv.x, e1 = av.y + adv.y, e2 = av.z + adv.z, e3 = av.w + adv.w;
            e0 = e0 > 0.f ? e0 : NEG_SLOPE * e0;
            e1 = e1 > 0.f ? e1 : NEG_SLOPE * e1;
            e2 = e2 > 0.f ? e2 : NEG_SLOPE * e2;
            e3 = e3 > 0.f ? e3 : NEG_SLOPE * e3;
            float w0 = __expf(e0), w1 = __expf(e1), w2 = __expf(e2), w3 = __expf(e3);
            *(float4*)ew_sh[w][l] = make_float4(w0, w1, w2, w3);
            ds0 += w0;
            ds1 += w1;
            ds2 += w2;
            ds3 += w3;
        }
        if (l < ACT) {
            int j = 0;
            for (; j + 3 < cnt; j += 4) {
                int s0 = sidx_sh[w][j + 0], s1 = sidx_sh[w][j + 1];
                int s2 = sidx_sh[w][j + 2], s3 = sidx_sh[w][j + 3];
                float w0 = ew_sh[w][j + 0][hd], w1 = ew_sh[w][j + 1][hd];
                float w2 = ew_sh[w][j + 2][hd], w3 = ew_sh[w][j + 3][hd];
                h4v v0 = *(const h4v*)(hbase + (long)s0 * HC);
                h4v v1 = *(const h4v*)(hbase + (long)s1 * HC);
                h4v v2 = *(const h4v*)(hbase + (long)s2 * HC);
                h4v v3 = *(const h4v*)(hbase + (long)s3 * HC);
                a0 += w0 * (float)v0[0];
                a1 += w0 * (float)v0[1];
                a2 += w0 * (float)v0[2];
                a3 += w0 * (float)v0[3];
                a0 += w1 * (float)v1[0];
                a1 += w1 * (float)v1[1];
                a2 += w1 * (float)v1[2];
                a3 += w1 * (float)v1[3];
                a0 += w2 * (float)v2[0];
                a1 += w2 * (float)v2[1];
                a2 += w2 * (float)v2[2];
                a3 += w2 * (float)v2[3];
                a0 += w3 * (float)v3[0];
                a1 += w3 * (float)v3[1];
                a2 += w3 * (float)v3[2];
                a3 += w3 * (float)v3[3];
            }
            for (; j < cnt; j++) {
                int s0 = sidx_sh[w][j];
                float w0 = ew_sh[w][j][hd];
                h4v v0 = *(const h4v*)(hbase + (long)s0 * HC);
                a0 += w0 * (float)v0[0];
                a1 += w0 * (float)v0[1];
                a2 += w0 * (float)v0[2];
                a3 += w0 * (float)v0[3];
            }
        }
    }

    // softmax denominators: full-wave reduction (inactive lanes contributed 0)
#pragma unroll
    for (int off = 1; off < 64; off <<= 1) {
        ds0 += __shfl_xor(ds0, off);
        ds1 += __shfl_xor(ds1, off);
        ds2 += __shfl_xor(ds2, off);
        ds3 += __shfl_xor(ds3, off);
    }

    if (l < ACT) {
        float dsel = hd == 0 ? ds0 : hd == 1 ? ds1 : hd == 2 ? ds2 : ds3;
        float inv = 1.0f / dsel;
        float4 bv = ((const float4*)bias)[l];
        float r0 = a0 * inv + bv.x;
        float r1 = a1 * inv + bv.y;
        float r2 = a2 * inv + bv.z;
        float r3 = a3 * inv + bv.w;
        if (RELU) {
            r0 = fmaxf(r0, 0.f);
            r1 = fmaxf(r1, 0.f);
            r2 = fmaxf(r2, 0.f);
            r3 = fmaxf(r3, 0.f);
        }
        OutT* op = out + (long)node * HC + 4 * l;
        if (sizeof(OutT) == 2) {
            h4v hv;
            hv[0] = (_Float16)r0;
            hv[1] = (_Float16)r1;
            hv[2] = (_Float16)r2;
            hv[3] = (_Float16)r3;
            *(h4v*)op = hv;
        } else {
            *(float4*)op = make_float4(r0, r1, r2, r3);
        }
    }
}

// ---------------- launch ----------------
extern "C" void kernel_launch(void* const* d_in, const int* in_sizes, int n_in, void* d_out,
                              int out_size, void* d_ws, size_t ws_size, hipStream_t stream) {
    const float* x = (const float*)d_in[0];
    const void* ei = d_in[1];
    const float* W1 = (const float*)d_in[2];
    const float* attS1 = (const float*)d_in[3];
    const float* attD1 = (const float*)d_in[4];
    const float* b1 = (const float*)d_in[5];
    const float* W2 = (const float*)d_in[6];
    const float* attS2 = (const float*)d_in[7];
    const float* attD2 = (const float*)d_in[8];
    const float* b2 = (const float*)d_in[9];
    float* out = (float*)d_out;

    int N = in_sizes[0] / F_IN;  // 50000
    int E = in_sizes[1] / 2;     // 800000
    int nb = (N + 255) / 256;
    int nw = (N + 3) / 4;  // wave-per-node grids

    // workspace layout (all 16B aligned)
    _Float16* xs_h = (_Float16*)d_ws;           // N*128
    _Float16* hb1 = xs_h + (size_t)N * F_IN;    // N*256
    _Float16* o1h = hb1 + (size_t)N * HC1;      // N*256
    _Float16* hb2 = o1h + (size_t)N * HC1;      // N*160
    _Float16* W1t = hb2 + (size_t)N * HC2;      // 256*128
    _Float16* W2t = W1t + HC1 * F_IN;           // 160*256
    float* as1 = (float*)(W2t + HC2 * HC1);     // N*4 each
    float* ad1 = as1 + (size_t)N * NHEAD;
    float* as2 = ad1 + (size_t)N * NHEAD;
    float* ad2 = as2 + (size_t)N * NHEAD;
    // stats/counts/cursor adjacent -> one memset
    float* stats = ad2 + (size_t)N * NHEAD;     // 256
    int* counts = (int*)(stats + 256);          // N
    int* cursor = counts + N;                   // N
    int* offsets = cursor + N;                  // N+1 (pad 4)
    int* csr = offsets + (N + 4);               // E+N
    int* blocksum = csr + (E + N);              // 256
    int* mode = blocksum + 256;                 // 1

    hipMemsetAsync(stats, 0, (256 + 2 * (size_t)N) * sizeof(int), stream);

    detect_mode_kernel<<<1, 256, 0, stream>>>((const unsigned int*)ei, 4096, mode);

    // standardize -> fp16
    colstats_kernel<<<nb, 256, 0, stream>>>(x, stats, N);
    finalize_stats_kernel<<<1, 128, 0, stream>>>(stats, N);
    int total4 = N * F_IN / 4;
    standardize_kernel<<<(total4 + 255) / 256, 256, 0, stream>>>(x, stats, xs_h, total4);

    // weights -> fp16 transposed (single dispatch)
    convert_w_kernel<<<(F_IN * HC1 + HC1 * HC2 + 255) / 256, 256, 0, stream>>>(W1, W1t, W2, W2t);

    // CSR by dst (shared by both layers)
    count_kernel<<<(E + 255) / 256, 256, 0, stream>>>(ei, mode, E, counts);
    scan_block_kernel<<<nb, 256, 0, stream>>>(counts, offsets, blocksum, N);
    scan_top_kernel<<<1, 256, 0, stream>>>(blocksum, nb);
    scan_add_kernel<<<nb, 256, 0, stream>>>(blocksum, offsets, N);
    fill_csr_kernel<<<(E + N + 255) / 256, 256, 0, stream>>>(ei, mode, E, N, offsets, cursor, csr);

    // layer 1
    gemm_f16_kernel<HC1, F_IN><<<(N + 63) / 64, 256, 0, stream>>>(xs_h, W1t, hb1, N);
    att_kernel<HC1><<<nw, 256, 0, stream>>>(hb1, attS1, attD1, as1, ad1, N);
    aggregate_kernel<HC1, true, _Float16>
        <<<nw, 256, 0, stream>>>(hb1, as1, ad1, offsets, csr, b1, o1h, N);

    // layer 2
    gemm_f16_kernel<HC2, HC1><<<(N + 63) / 64, 256, 0, stream>>>(o1h, W2t, hb2, N);
    att_kernel<HC2><<<nw, 256, 0, stream>>>(hb2, attS2, attD2, as2, ad2, N);
    aggregate_kernel<HC2, false, float>
        <<<nw, 256, 0, stream>>>(hb2, as2, ad2, offsets, csr, b2, out, N);
}

// Round 5
// 405.666 us; speedup vs baseline: 2.2887x; 1.1125x over previous
//
#include <hip/hip_runtime.h>
#include <math.h>

#define NEG_SLOPE 0.2f

constexpr int F_IN  = 128;
constexpr int HC1   = 256;  // H*HID
constexpr int HC2   = 160;  // H*CLS
constexpr int NHEAD = 4;

typedef _Float16 h8v __attribute__((ext_vector_type(8)));
typedef _Float16 h4v __attribute__((ext_vector_type(4)));
typedef float f4v __attribute__((ext_vector_type(4)));

// f32 += f16(lo/hi of packed) * f32 — single VOP3P instruction
#define FMIX_LO(acc, pk, wt) \
    asm("v_fma_mix_f32 %0, %1, %2, %0 op_sel:[0,0,0] op_sel_hi:[1,0,0]" \
        : "+v"(acc) : "v"(pk), "v"(wt))
#define FMIX_HI(acc, pk, wt) \
    asm("v_fma_mix_f32 %0, %1, %2, %0 op_sel:[1,0,0] op_sel_hi:[1,0,0]" \
        : "+v"(acc) : "v"(pk), "v"(wt))

__device__ __forceinline__ int edge_val(const void* p, int m64, long long i) {
    if (m64) return (int)((const long long*)p)[i];
    return ((const int*)p)[i];
}

// ---------------- init: zero stats+counts, block 0 detects edge dtype ----------------
__global__ void init_kernel(const unsigned int* __restrict__ ei_words, int* __restrict__ zbase,
                            int zcount, int* __restrict__ mode) {
    int gid = blockIdx.x * 256 + threadIdx.x;
    if (gid < zcount) zbase[gid] = 0;
    if (blockIdx.x == 0) {
        // int64 edge_index with values < 2^31 -> all odd 32-bit words zero
        __shared__ unsigned int red[256];
        unsigned int v = 0;
        for (int i = 1 + 2 * (int)threadIdx.x; i < 4096; i += 512) v |= ei_words[i];
        red[threadIdx.x] = v;
        __syncthreads();
        for (int off = 128; off > 0; off >>= 1) {
            if (threadIdx.x < off) red[threadIdx.x] |= red[threadIdx.x + off];
            __syncthreads();
        }
        if (threadIdx.x == 0) *mode = (red[0] == 0u) ? 1 : 0;
    }
}

// ---------------- column stats (raw sums; finalize fused into standardize) ----------------
__global__ void colstats_kernel(const float* __restrict__ x, float* __restrict__ stats, int N) {
    int col = threadIdx.x & 127;
    int r0 = blockIdx.x * 256;
    int rend = min(r0 + 256, N);
    float s = 0.f, q = 0.f;
    for (int r = r0 + (int)(threadIdx.x >> 7); r < rend; r += 2) {
        float v = x[(long)r * F_IN + col];
        s += v;
        q += v * v;
    }
    __shared__ float sh[256];
    sh[threadIdx.x] = s;
    __syncthreads();
    if (threadIdx.x < 128) atomicAdd(&stats[col], sh[threadIdx.x] + sh[threadIdx.x + 128]);
    __syncthreads();
    sh[threadIdx.x] = q;
    __syncthreads();
    if (threadIdx.x < 128) atomicAdd(&stats[128 + col], sh[threadIdx.x] + sh[threadIdx.x + 128]);
}

// standardize + fp16 convert; mean/inv-std computed inline from raw sums
__global__ void standardize_kernel(const float* __restrict__ x, const float* __restrict__ stats,
                                   _Float16* __restrict__ xs, int total4, float invN,
                                   float invN1) {
    int i = blockIdx.x * blockDim.x + threadIdx.x;
    if (i >= total4) return;
    int c = (i * 4) & (F_IN - 1);
    float4 s4 = *(const float4*)&stats[c];
    float4 q4 = *(const float4*)&stats[128 + c];
    float4 v = ((const float4*)x)[i];
    h4v o;
    o[0] = (_Float16)((v.x - s4.x * invN) / sqrtf((q4.x - s4.x * s4.x * invN) * invN1));
    o[1] = (_Float16)((v.y - s4.y * invN) / sqrtf((q4.y - s4.y * s4.y * invN) * invN1));
    o[2] = (_Float16)((v.z - s4.z * invN) / sqrtf((q4.z - s4.z * s4.z * invN) * invN1));
    o[3] = (_Float16)((v.w - s4.w * invN) / sqrtf((q4.w - s4.w * s4.w * invN) * invN1));
    ((h4v*)xs)[i] = o;
}

// ---------------- weights -> fp16 transposed, with att columns appended ----------------
// Btx layout [Nc+16][K]: rows 0..Nc-1 = W^T; rows Nc..Nc+3 = W·att_src per head;
// rows Nc+4..Nc+7 = W·att_dst per head; rows Nc+8..Nc+15 = 0.
__global__ void convert_w_kernel(const float* __restrict__ W1, const float* __restrict__ aS1,
                                 const float* __restrict__ aD1, _Float16* __restrict__ B1x,
                                 const float* __restrict__ W2, const float* __restrict__ aS2,
                                 const float* __restrict__ aD2, _Float16* __restrict__ B2x) {
    constexpr int T1 = (HC1 + 16) * F_IN;
    constexpr int T2 = (HC2 + 16) * HC1;
    int idx = blockIdx.x * blockDim.x + threadIdx.x;
    if (idx < T1) {
        int n = idx / F_IN, k = idx - n * F_IN;
        float v = 0.f;
        if (n < HC1) {
            v = W1[k * HC1 + n];
        } else {
            int n2 = n - HC1;
            if (n2 < 8) {
                int hd = n2 & 3;
                const float* a = (n2 < 4) ? aS1 : aD1;
                for (int c = 0; c < 64; c++) v += W1[k * HC1 + hd * 64 + c] * a[hd * 64 + c];
            }
        }
        B1x[n * F_IN + k] = (_Float16)v;
    } else if (idx < T1 + T2) {
        int i2 = idx - T1;
        int n = i2 / HC1, k = i2 - n * HC1;
        float v = 0.f;
        if (n < HC2) {
            v = W2[k * HC2 + n];
        } else {
            int n2 = n - HC2;
            if (n2 < 8) {
                int hd = n2 & 3;
                const float* a = (n2 < 4) ? aS2 : aD2;
                for (int c = 0; c < 40; c++) v += W2[k * HC2 + hd * 40 + c] * a[hd * 40 + c];
            }
        }
        B2x[n * HC1 + k] = (_Float16)v;
    }
}

// ---------------- MFMA f16 GEMM with fused attention scores ----------------
// C[M][Nc] = A[M][K] * Btx[0..Nc-1][K]^T; extra tile (rows Nc..Nc+15) yields
// as/ad per head in fp32 accumulators (exact reassociation of h·att).
template <int Nc, int K>
__global__ __launch_bounds__(256) void gemm_att_kernel(const _Float16* __restrict__ A,
                                                       const _Float16* __restrict__ Btx,
                                                       _Float16* __restrict__ C_,
                                                       float* __restrict__ as_,
                                                       float* __restrict__ ad_, int M) {
    constexpr int NT = Nc / 16;
    constexpr int NTT = NT + 1;
    constexpr int KT = K / 32;
    int w = threadIdx.x >> 6;
    int l = threadIdx.x & 63;
    int quad = l >> 4, lan = l & 15;
    int row = blockIdx.x * 64 + w * 16 + lan;
    int arow = min(row, M - 1);
    f4v acc[NTT] = {};
    const _Float16* Aptr = A + (long)arow * K + quad * 8;
#pragma unroll
    for (int k0 = 0; k0 < KT; k0++) {
        h8v af = *(const h8v*)(Aptr + k0 * 32);
#pragma unroll
        for (int ct = 0; ct < NTT; ct++) {
            const _Float16* Bptr = Btx + (long)(ct * 16 + lan) * K + k0 * 32 + quad * 8;
            h8v bf = *(const h8v*)Bptr;
            acc[ct] = __builtin_amdgcn_mfma_f32_16x16x32_f16(af, bf, acc[ct], 0, 0, 0);
        }
    }
    int orow = blockIdx.x * 64 + w * 16 + quad * 4;
#pragma unroll
    for (int r = 0; r < 4; r++) {
        int gr = orow + r;
        if (gr < M) {
            _Float16* out = C_ + (long)gr * Nc + lan;
#pragma unroll
            for (int ct = 0; ct < NT; ct++) out[ct * 16] = (_Float16)acc[ct][r];
            float av = acc[NT][r];
            if (lan < 4)
                as_[gr * 4 + lan] = av;
            else if (lan < 8)
                ad_[gr * 4 + lan - 4] = av;
        }
    }
}

// ---------------- CSR build over dst ----------------
__global__ void count_kernel(const void* __restrict__ ei, const int* __restrict__ mode, int E,
                             int* __restrict__ counts, int* __restrict__ pos) {
    int e = blockIdx.x * blockDim.x + threadIdx.x;
    if (e >= E) return;
    int d = edge_val(ei, *mode, (long long)E + e);
    pos[e] = atomicAdd(&counts[d], 1);
}

// self-loop (+1 per node) folded in
__global__ void scan_block_kernel(const int* __restrict__ counts, int* __restrict__ offsets,
                                  int* __restrict__ blocksum, int N) {
    int t = threadIdx.x;
    int i = blockIdx.x * 256 + t;
    int v = (i < N) ? counts[i] + 1 : 0;
    int lane = t & 63, w = t >> 6;
    int x = v;
#pragma unroll
    for (int d = 1; d < 64; d <<= 1) {
        int y = __shfl_up(x, d);
        if (lane >= d) x += y;
    }
    __shared__ int wsum[4];
    if (lane == 63) wsum[w] = x;
    __syncthreads();
    int base = 0;
    for (int k = 0; k < w; k++) base += wsum[k];
    int incl = x + base;
    if (i < N) offsets[i + 1] = incl;
    if (t == 255) blocksum[blockIdx.x] = incl;
}

// every block re-scans the (<=256) block sums, then applies its own base
__global__ void scan_add_kernel(const int* __restrict__ blocksum, int* __restrict__ offsets, int N,
                                int nb) {
    int t = threadIdx.x;
    int v = (t < nb) ? blocksum[t] : 0;
    int lane = t & 63, w = t >> 6;
    int x = v;
#pragma unroll
    for (int d = 1; d < 64; d <<= 1) {
        int y = __shfl_up(x, d);
        if (lane >= d) x += y;
    }
    __shared__ int wsum[4];
    __shared__ int excl[256];
    if (lane == 63) wsum[w] = x;
    __syncthreads();
    int base = 0;
    for (int k = 0; k < w; k++) base += wsum[k];
    excl[t] = x + base - v;
    __syncthreads();
    int myb = excl[blockIdx.x];
    int i = blockIdx.x * 256 + t;
    if (i < N) offsets[i + 1] += myb;
    if (i == 0) offsets[0] = 0;
}

// no atomics: slot = offsets[d] + 1 + pos[e]; slot offsets[d] is the self-loop
__global__ void fill_csr_kernel(const void* __restrict__ ei, const int* __restrict__ mode, int E,
                                int N, const int* __restrict__ offsets,
                                const int* __restrict__ pos, int* __restrict__ csr) {
    int e = blockIdx.x * blockDim.x + threadIdx.x;
    if (e < E) {
        int m = *mode;
        int s = edge_val(ei, m, e);
        int d = edge_val(ei, m, (long long)E + e);
        csr[offsets[d] + 1 + pos[e]] = s;
    } else if (e < E + N) {
        int n = e - E;
        csr[offsets[n]] = n;
    }
}

// ---------------- softmax + aggregation: one wave per node, zero barriers ----------------
template <int HC, bool RELU, typename OutT>
__global__ __launch_bounds__(256) void aggregate_kernel(
    const _Float16* __restrict__ hb, const float* __restrict__ a_src,
    const float* __restrict__ a_dst, const int* __restrict__ offsets,
    const int* __restrict__ csr_src, const float* __restrict__ bias, OutT* __restrict__ out,
    int Ntot) {
    constexpr int ACT = HC / 4;       // active gather lanes (64 or 40)
    constexpr int CHPH = HC / NHEAD;  // channels per head
    int w = threadIdx.x >> 6, l = threadIdx.x & 63;
    int node = blockIdx.x * 4 + w;
    if (node >= Ntot) return;  // wave-uniform exit

    __shared__ __align__(16) int sidx_sh[4][64];      // byte offsets into hb
    __shared__ __align__(16) float ew_sh[4][64][4];   // per-edge per-head exp weights

    int start = offsets[node], end = offsets[node + 1];
    int deg = end - start;
    float4 adv = ((const float4*)a_dst)[node];
    const int hd = min((4 * l) / CHPH, 3);
    const char* hbl = (const char*)hb + 8 * l;  // this lane's 4-channel slice

    float ds0 = 0.f, ds1 = 0.f, ds2 = 0.f, ds3 = 0.f;
    float a0 = 0.f, a1 = 0.f, a2 = 0.f, a3 = 0.f;

    for (int base = 0; base < deg; base += 64) {
        int cnt = min(64, deg - base);
        if (l < cnt) {
            int s = csr_src[start + base + l];
            sidx_sh[w][l] = s * (HC * 2);
            float4 av = ((const float4*)a_src)[s];
            float e0 = av.x + adv.x, e1 = av.y + adv.y, e2 = av.z + adv.z, e3 = av.w + adv.w;
            e0 = fmaxf(e0, NEG_SLOPE * e0);
            e1 = fmaxf(e1, NEG_SLOPE * e1);
            e2 = fmaxf(e2, NEG_SLOPE * e2);
            e3 = fmaxf(e3, NEG_SLOPE * e3);
            float w0 = __expf(e0), w1 = __expf(e1), w2 = __expf(e2), w3 = __expf(e3);
            *(float4*)ew_sh[w][l] = make_float4(w0, w1, w2, w3);
            ds0 += w0;
            ds1 += w1;
            ds2 += w2;
            ds3 += w3;
        }
        int j = 0;
        for (; j + 3 < cnt; j += 4) {
            int4 o4 = *(const int4*)&sidx_sh[w][j];  // uniform addr -> b128 broadcast
            float w0 = ew_sh[w][j + 0][hd];
            float w1 = ew_sh[w][j + 1][hd];
            float w2 = ew_sh[w][j + 2][hd];
            float w3 = ew_sh[w][j + 3][hd];
            if (l < ACT) {
                int2 p0 = *(const int2*)(hbl + o4.x);
                int2 p1 = *(const int2*)(hbl + o4.y);
                int2 p2 = *(const int2*)(hbl + o4.z);
                int2 p3 = *(const int2*)(hbl + o4.w);
                FMIX_LO(a0, p0.x, w0);
                FMIX_HI(a1, p0.x, w0);
                FMIX_LO(a2, p0.y, w0);
                FMIX_HI(a3, p0.y, w0);
                FMIX_LO(a0, p1.x, w1);
                FMIX_HI(a1, p1.x, w1);
                FMIX_LO(a2, p1.y, w1);
                FMIX_HI(a3, p1.y, w1);
                FMIX_LO(a0, p2.x, w2);
                FMIX_HI(a1, p2.x, w2);
                FMIX_LO(a2, p2.y, w2);
                FMIX_HI(a3, p2.y, w2);
                FMIX_LO(a0, p3.x, w3);
                FMIX_HI(a1, p3.x, w3);
                FMIX_LO(a2, p3.y, w3);
                FMIX_HI(a3, p3.y, w3);
            }
        }
        for (; j < cnt; j++) {
            int off = sidx_sh[w][j];
            float w0 = ew_sh[w][j][hd];
            if (l < ACT) {
                int2 p0 = *(const int2*)(hbl + off);
                FMIX_LO(a0, p0.x, w0);
                FMIX_HI(a1, p0.x, w0);
                FMIX_LO(a2, p0.y, w0);
                FMIX_HI(a3, p0.y, w0);
            }
        }
    }

    // softmax denominators: full-wave reduction (lanes >= cnt contributed 0)
#pragma unroll
    for (int off = 1; off < 64; off <<= 1) {
        ds0 += __shfl_xor(ds0, off);
        ds1 += __shfl_xor(ds1, off);
        ds2 += __shfl_xor(ds2, off);
        ds3 += __shfl_xor(ds3, off);
    }

    if (l < ACT) {
        float dsel = hd == 0 ? ds0 : hd == 1 ? ds1 : hd == 2 ? ds2 : ds3;
        float inv = 1.0f / dsel;
        float4 bv = ((const float4*)bias)[l];
        float r0 = a0 * inv + bv.x;
        float r1 = a1 * inv + bv.y;
        float r2 = a2 * inv + bv.z;
        float r3 = a3 * inv + bv.w;
        if (RELU) {
            r0 = fmaxf(r0, 0.f);
            r1 = fmaxf(r1, 0.f);
            r2 = fmaxf(r2, 0.f);
            r3 = fmaxf(r3, 0.f);
        }
        OutT* op = out + (long)node * HC + 4 * l;
        if (sizeof(OutT) == 2) {
            h4v hv;
            hv[0] = (_Float16)r0;
            hv[1] = (_Float16)r1;
            hv[2] = (_Float16)r2;
            hv[3] = (_Float16)r3;
            *(h4v*)op = hv;
        } else {
            *(float4*)op = make_float4(r0, r1, r2, r3);
        }
    }
}

// ---------------- launch ----------------
extern "C" void kernel_launch(void* const* d_in, const int* in_sizes, int n_in, void* d_out,
                              int out_size, void* d_ws, size_t ws_size, hipStream_t stream) {
    const float* x = (const float*)d_in[0];
    const void* ei = d_in[1];
    const float* W1 = (const float*)d_in[2];
    const float* attS1 = (const float*)d_in[3];
    const float* attD1 = (const float*)d_in[4];
    const float* b1 = (const float*)d_in[5];
    const float* W2 = (const float*)d_in[6];
    const float* attS2 = (const float*)d_in[7];
    const float* attD2 = (const float*)d_in[8];
    const float* b2 = (const float*)d_in[9];
    float* out = (float*)d_out;

    int N = in_sizes[0] / F_IN;  // 50000
    int E = in_sizes[1] / 2;     // 800000
    int nb = (N + 255) / 256;
    int nw = (N + 3) / 4;

    // workspace layout (all 16B aligned)
    _Float16* xs_h = (_Float16*)d_ws;             // N*128
    _Float16* hb1 = xs_h + (size_t)N * F_IN;      // N*256
    _Float16* o1h = hb1 + (size_t)N * HC1;        // N*256
    _Float16* hb2 = o1h + (size_t)N * HC1;        // N*160 (pos[] overlays this early)
    _Float16* B1x = hb2 + (size_t)N * HC2;        // 272*128
    _Float16* B2x = B1x + (HC1 + 16) * F_IN;      // 176*256
    float* as1 = (float*)(B2x + (HC2 + 16) * HC1);
    float* ad1 = as1 + (size_t)N * NHEAD;
    float* as2 = ad1 + (size_t)N * NHEAD;
    float* ad2 = as2 + (size_t)N * NHEAD;
    float* stats = ad2 + (size_t)N * NHEAD;       // 256
    int* counts = (int*)(stats + 256);            // N (zeroed with stats)
    int* offsets = counts + N;                    // N+1 (pad 4)
    int* csr = offsets + (N + 4);                 // E+N
    int* blocksum = csr + (E + N);                // 256
    int* mode = blocksum + 256;                   // 1
    int* pos = (int*)hb2;  // E ints; dead before gemm2 writes hb2

    // 1. zero stats+counts, detect edge dtype
    init_kernel<<<(N + 256 + 255) / 256, 256, 0, stream>>>((const unsigned int*)ei, (int*)stats,
                                                           256 + N, mode);
    // 2-3. standardize -> fp16
    colstats_kernel<<<nb, 256, 0, stream>>>(x, stats, N);
    int total4 = N * F_IN / 4;
    standardize_kernel<<<(total4 + 255) / 256, 256, 0, stream>>>(
        x, stats, xs_h, total4, 1.0f / (float)N, 1.0f / (float)(N - 1));
    // 4. weights -> fp16 transposed + att columns
    constexpr int TCV = (HC1 + 16) * F_IN + (HC2 + 16) * HC1;
    convert_w_kernel<<<(TCV + 255) / 256, 256, 0, stream>>>(W1, attS1, attD1, B1x, W2, attS2,
                                                            attD2, B2x);
    // 5-8. CSR by dst (shared by both layers)
    count_kernel<<<(E + 255) / 256, 256, 0, stream>>>(ei, mode, E, counts, pos);
    scan_block_kernel<<<nb, 256, 0, stream>>>(counts, offsets, blocksum, N);
    scan_add_kernel<<<nb, 256, 0, stream>>>(blocksum, offsets, N, nb);
    fill_csr_kernel<<<(E + N + 255) / 256, 256, 0, stream>>>(ei, mode, E, N, offsets, pos, csr);

    // 9-10. layer 1 (att scores fused into GEMM)
    gemm_att_kernel<HC1, F_IN>
        <<<(N + 63) / 64, 256, 0, stream>>>(xs_h, B1x, hb1, as1, ad1, N);
    aggregate_kernel<HC1, true, _Float16>
        <<<nw, 256, 0, stream>>>(hb1, as1, ad1, offsets, csr, b1, o1h, N);

    // 11-12. layer 2
    gemm_att_kernel<HC2, HC1>
        <<<(N + 63) / 64, 256, 0, stream>>>(o1h, B2x, hb2, as2, ad2, N);
    aggregate_kernel<HC2, false, float>
        <<<nw, 256, 0, stream>>>(hb2, as2, ad2, offsets, csr, b2, out, N);
}